// Round 1
// baseline (406.130 us; speedup 1.0000x reference)
//
#include <hip/hip_runtime.h>
#include <math.h>

#define N_    512
#define H_    40
#define B_N   8
#define D_    384
#define O_    62
#define RW    392     // ring width: D + 8 batch shifts
#define SMAX  13      // cap on delay==0 entries per column (E[cnt]=1.33, P(>12)~1e-8)

// ---- output flat offsets (f32 elements, reference return order) ----
#define OUT_STATE 0        // (N,6)   3072
#define OUT_EEG   3072     // (O,B)   496
#define OUT_ES    3568     // (N,B)   4096
#define OUT_IS    7664
#define OUT_MS    11760
#define OUT_EVS   15856
#define OUT_IVS   19952
#define OUT_MVS   24048
#define OUT_HE    28144    // (N,D)   196608

// k0: transpose input/noise_in (N,H,B) -> step-major (b*H+h)*N + i (coalesced per-step reads)
__global__ void k0_transpose(const float* __restrict__ input, const float* __restrict__ noise_in,
                             float* __restrict__ ut, float* __restrict__ nzt) {
    int bh = blockIdx.x;            // 0..319
    int b = bh & 7, h = bh >> 3;
    int dst = (b * H_ + h) * N_;
    for (int i = threadIdx.x; i < N_; i += blockDim.x) {
        ut[dst + i]  = input[i * (H_ * B_N) + h * B_N + b];
        nzt[dst + i] = noise_in[i * (H_ * B_N) + h * B_N + b];
    }
}

// k1: per-row i: ws row (symmetric log1p), row-sum, sum-of-squares, ring init,
//     and deterministic (ascending-j) sparse list of {j : delays[j,i]==0}.
__global__ void k1_prep(const float* __restrict__ wbb, const float* __restrict__ sc,
                        const float* __restrict__ hE_in, const int* __restrict__ delays,
                        float* __restrict__ ws, float* __restrict__ ring,
                        float* __restrict__ rowsum_ws, float* __restrict__ sumsq,
                        float* __restrict__ s0w, int* __restrict__ s0j, int* __restrict__ s0c) {
    int i = blockIdx.x;
    int t = threadIdx.x;            // 256 threads
    __shared__ float wsrow[N_];
    __shared__ float red[256];
    __shared__ int cnt_c[8];
    __shared__ int cnt_base[8];

    float ssq = 0.f, rsum = 0.f;
    for (int j = t; j < N_; j += 256) {
        float w = 0.5f * (expf(wbb[i * N_ + j]) * sc[i * N_ + j] +
                          expf(wbb[j * N_ + i]) * sc[j * N_ + i]);
        float v = log1pf(w);
        ws[i * N_ + j] = v;
        wsrow[j] = v;
        ssq += v * v;
        rsum += v;
    }
    // ring init: slots 8..391 = hE_in cols 0..383
    for (int k = t; k < D_; k += 256) ring[i * RW + 8 + k] = hE_in[i * D_ + k];

    red[t] = ssq; __syncthreads();
    for (int s = 128; s > 0; s >>= 1) { if (t < s) red[t] += red[t + s]; __syncthreads(); }
    if (t == 0) sumsq[i] = red[0];
    __syncthreads();
    red[t] = rsum; __syncthreads();
    for (int s = 128; s > 0; s >>= 1) { if (t < s) red[t] += red[t + s]; __syncthreads(); }
    if (t == 0) rowsum_ws[i] = red[0];
    __syncthreads();

    // sparse build: j = t (chunks 0..3), j = t+256 (chunks 4..7); wave ballots keep j order
    int wave = t >> 6, lane = t & 63;
    bool f1 = (delays[t * N_ + i] == 0);
    bool f2 = (delays[(t + 256) * N_ + i] == 0);
    unsigned long long m1 = __ballot(f1);
    unsigned long long m2 = __ballot(f2);
    if (lane == 0) { cnt_c[wave] = __popcll(m1); cnt_c[wave + 4] = __popcll(m2); }
    __syncthreads();
    if (t == 0) {
        int s = 0;
        for (int c = 0; c < 8; c++) { cnt_base[c] = s; s += cnt_c[c]; }
        s0c[i] = (s > SMAX) ? SMAX : s;
    }
    __syncthreads();
    unsigned long long below = (lane == 0) ? 0ull : ((~0ull) >> (64 - lane));
    if (f1) {
        int pos = cnt_base[wave] + __popcll(m1 & below);
        if (pos < SMAX) { s0j[i * SMAX + pos] = t;       s0w[i * SMAX + pos] = wsrow[t]; }
    }
    if (f2) {
        int pos = cnt_base[wave + 4] + __popcll(m2 & below);
        if (pos < SMAX) { s0j[i * SMAX + pos] = t + 256; s0w[i * SMAX + pos] = wsrow[t + 256]; }
    }
}

// k2: reduce norm, scale rowsum + sparse weights, init state from hx (SoA)
__global__ void k2_finish(const float* __restrict__ hx, const float* __restrict__ sumsq,
                          const float* __restrict__ rowsum_ws, float* __restrict__ invn,
                          float* __restrict__ rowsum_n, float* __restrict__ s0w,
                          const int* __restrict__ s0c, float* __restrict__ state) {
    __shared__ float red[N_];
    __shared__ float inv_s;
    int t = threadIdx.x;            // 512 threads
    red[t] = sumsq[t]; __syncthreads();
    for (int s = 256; s > 0; s >>= 1) { if (t < s) red[t] += red[t + s]; __syncthreads(); }
    if (t == 0) { float iv = 1.0f / sqrtf(red[0]); invn[0] = iv; inv_s = iv; }
    __syncthreads();
    float iv = inv_s;
    rowsum_n[t] = rowsum_ws[t] * iv;
    int c = s0c[t];
    for (int k = 0; k < c; k++) s0w[t * SMAX + k] *= iv;
    for (int cc = 0; cc < 6; cc++) state[cc * N_ + t] = hx[t * 6 + cc];
}

// base_b[i] = sum_{j, d_ji>=1} ws[j,i] * ring[j, (8-b)+d_ji]   (unscaled; x invnorm in hidden)
// 64 blocks = 8 i-blocks x 8 j-blocks; partials written per j-block (no atomics).
__global__ void k_base(const float* __restrict__ ws, const int* __restrict__ delays,
                       const float* __restrict__ ring, float* __restrict__ bp, int b) {
    int ib = blockIdx.x >> 3, jb = blockIdx.x & 7;
    int wave = threadIdx.x >> 6, lane = threadIdx.x & 63;
    int i = ib * 64 + lane;
    int off = 8 - b;
    float acc = 0.f;
    int j0 = jb * 64 + wave * 16;
    for (int jj = 0; jj < 16; jj++) {
        int j = j0 + jj;
        int d = delays[j * N_ + i];          // coalesced
        float w = ws[j * N_ + i];            // coalesced (symmetric)
        float v = ring[j * RW + off + d];    // gather within one ring row (hot)
        if (d > 0) acc += w * v;
    }
    __shared__ float part[4][64];
    part[wave][lane] = acc; __syncthreads();
    if (wave == 0) {
        float s = part[0][lane] + part[1][lane] + part[2][lane] + part[3][lane];
        bp[jb * N_ + i] = s;
    }
}

// 40 hidden Euler steps for batch b; one WG, thread i = node i.
__global__ void __launch_bounds__(512)
k_hidden(const float* __restrict__ ut, const float* __restrict__ nzt,
         const float* __restrict__ hE_in, const float* __restrict__ lm,
         const float* __restrict__ bp, const float* __restrict__ invn,
         const float* __restrict__ rowsum_n, const float* __restrict__ s0w_g,
         const int* __restrict__ s0j_g, const int* __restrict__ s0c,
         float* __restrict__ state, float* __restrict__ ring,
         float* __restrict__ out, int b) {
    __shared__ float curr[2][N_];
    __shared__ float s0w_l[N_ * SMAX];
    __shared__ int   s0j_l[N_ * SMAX];
    int i = threadIdx.x;

    for (int k = i; k < N_ * SMAX; k += N_) { s0w_l[k] = s0w_g[k]; s0j_l[k] = s0j_g[k]; }

    float M  = state[0 * N_ + i], E  = state[1 * N_ + i], I  = state[2 * N_ + i];
    float Mv = state[3 * N_ + i], Ev = state[4 * N_ + i], Iv = state[5 * N_ + i];
    float iv = invn[0];
    float base = 0.f;
#pragma unroll
    for (int p = 0; p < 8; p++) base += bp[p * N_ + i];
    base *= iv;
    float rs  = rowsum_n[i];
    int   cnt = s0c[i];
    float hE0 = hE_in[i * D_];               // only used at (b==0, h==0)
    const float* up  = ut  + (size_t)b * H_ * N_;
    const float* nzp = nzt + (size_t)b * H_ * N_;
    float u_c  = up[i];
    float nz_c = nzp[i];
    __syncthreads();                         // lists ready

    for (int h = 0; h < H_; h++) {
        int hn = (h < H_ - 1) ? h + 1 : h;   // prefetch next step's inputs
        float u_n  = up[hn * N_ + i];
        float nz_n = nzp[hn * N_ + i];

        float ei = E - I;
        curr[h & 1][i] = (b == 0 && h == 0) ? hE0 : ei;
        __syncthreads();

        float sp = 0.f;
        for (int k = 0; k < cnt; k++)
            sp += s0w_l[i * SMAX + k] * curr[h & 1][s0j_l[i * SMAX + k]];
        float LEd = base + sp;

        float rM = 5.0f / (1.0f + __expf(0.56f * (6.0f - ei)));
        float rE = 540.0f  / (1.0f + __expf(0.56f * (6.0f - 135.0f * M)));   // c2*sigmoid(c1*M)
        float rI = 168.75f / (1.0f + __expf(0.56f * (6.0f - 33.75f * M)));   // c4*sigmoid(c3*M)
        float coupled  = 100.0f * (LEd - rs * ei);
        float coupling = 500.0f * tanhf(coupled * 0.002f);

        float Mn = M + 1e-4f * Mv;
        float En = E + 1e-4f * Ev;
        float In = I + 1e-4f * Iv;
        float Mvn = Mv + 1e-4f * (325.0f * rM - 200.0f * Mv - 10000.0f * M);
        float Evn = Ev + 1e-4f * (325.0f * (rE + coupling + 5.0f * u_c + 100.0f * nz_c + 0.5f)
                                  - 200.0f * Ev - 10000.0f * E);
        float Ivn = Iv + 1e-4f * (1100.0f * rI - 100.0f * Iv - 2500.0f * I);
        M = Mn; E = En; I = In; Mv = Mvn; Ev = Evn; Iv = Ivn;
        u_c = u_n; nz_c = nz_n;
    }

    float eif = E - I;
    out[OUT_ES  + i * B_N + b] = E;
    out[OUT_IS  + i * B_N + b] = I;
    out[OUT_MS  + i * B_N + b] = M;
    out[OUT_EVS + i * B_N + b] = Ev;
    out[OUT_IVS + i * B_N + b] = Iv;
    out[OUT_MVS + i * B_N + b] = Mv;
    ring[i * RW + (7 - b)] = eif;            // new col 0 after shift
    ring[i * RW + (8 - b)] = eif;            // old col 0's final (live) value
    state[0 * N_ + i] = M;  state[1 * N_ + i] = E;  state[2 * N_ + i] = I;
    state[3 * N_ + i] = Mv; state[4 * N_ + i] = Ev; state[5 * N_ + i] = Iv;
    if (b == B_N - 1) {
        out[i * 6 + 0] = M;  out[i * 6 + 1] = E;  out[i * 6 + 2] = I;
        out[i * 6 + 3] = Mv; out[i * 6 + 4] = Ev; out[i * 6 + 5] = Iv;
    }

    // eeg = 0.0005 * lm @ (E-I): 8 waves x rows, shuffle-reduce
    curr[0][i] = eif;
    __syncthreads();
    int wave = i >> 6, lane = i & 63;
    for (int o = wave; o < O_; o += 8) {
        float p = 0.f;
#pragma unroll
        for (int m = 0; m < 8; m++) {
            int idx = lane + 64 * m;
            p += lm[o * N_ + idx] * curr[0][idx];
        }
        for (int off2 = 32; off2 > 0; off2 >>= 1) p += __shfl_down(p, off2, 64);
        if (lane == 0) out[OUT_EEG + o * B_N + b] = 0.0005f * p;
    }
}

__global__ void k_final(const float* __restrict__ ring, float* __restrict__ out) {
    int i = blockIdx.x;
    for (int k = threadIdx.x; k < D_; k += 256)
        out[OUT_HE + i * D_ + k] = ring[i * RW + k];
}

extern "C" void kernel_launch(void* const* d_in, const int* in_sizes, int n_in,
                              void* d_out, int out_size, void* d_ws, size_t ws_size,
                              hipStream_t stream) {
    const float* input    = (const float*)d_in[0];
    const float* noise_in = (const float*)d_in[1];
    // d_in[2] = noise_out: unused by the reference
    const float* hx       = (const float*)d_in[3];
    const float* hE       = (const float*)d_in[4];
    const float* wbb      = (const float*)d_in[5];
    const float* sc       = (const float*)d_in[6];
    const float* lm       = (const float*)d_in[7];
    const int*   delays   = (const int*)d_in[8];
    float* out = (float*)d_out;

    // workspace carve-up (floats)
    float* F    = (float*)d_ws;
    float* ut   = F;                      // 163840
    float* nzt  = ut + 163840;            // 163840
    float* wsm  = nzt + 163840;           // 262144
    float* ring = wsm + 262144;           // 200704 (512 x 392)
    float* bp   = ring + 200704;          // 4096   (8 x 512 partials)
    float* rsw  = bp + 4096;              // 512
    float* ssq  = rsw + 512;              // 512
    float* invn = ssq + 512;              // 8
    float* rsn  = invn + 8;               // 512
    float* s0w  = rsn + 512;              // 512*13
    int*   s0j  = (int*)(s0w + N_ * SMAX);// 512*13
    int*   s0c  = s0j + N_ * SMAX;        // 512
    float* state = (float*)(s0c + N_);    // 3072

    k0_transpose<<<H_ * B_N, 256, 0, stream>>>(input, noise_in, ut, nzt);
    k1_prep<<<N_, 256, 0, stream>>>(wbb, sc, hE, delays, wsm, ring, rsw, ssq, s0w, s0j, s0c);
    k2_finish<<<1, N_, 0, stream>>>(hx, ssq, rsw, invn, rsn, s0w, s0c, state);
    for (int b = 0; b < B_N; b++) {
        k_base<<<64, 256, 0, stream>>>(wsm, delays, ring, bp, b);
        k_hidden<<<1, N_, 0, stream>>>(ut, nzt, hE, lm, bp, invn, rsn,
                                       s0w, s0j, s0c, state, ring, out, b);
    }
    k_final<<<N_, 256, 0, stream>>>(ring, out);
}

// Round 2
// 325.561 us; speedup vs baseline: 1.2475x; 1.2475x over previous
//
#include <hip/hip_runtime.h>
#include <math.h>

#define N_    512
#define H_    40
#define B_N   8
#define D_    384
#define O_    62
#define RW    392     // ring width: D + 8 batch shifts
#define SMAX  13      // cap on delay==0 entries per column (E[cnt]=1.33, P(>12)~1e-8)

// ---- output flat offsets (f32 elements, reference return order) ----
#define OUT_STATE 0        // (N,6)   3072
#define OUT_EEG   3072     // (O,B)   496
#define OUT_ES    3568     // (N,B)   4096
#define OUT_IS    7664
#define OUT_MS    11760
#define OUT_EVS   15856
#define OUT_IVS   19952
#define OUT_MVS   24048
#define OUT_HE    28144    // (N,D)   196608

// k0: fuse input+noise into drive = 325*(5u + 100nz + 0.5), step-major layout
__global__ void k0_drive(const float* __restrict__ input, const float* __restrict__ noise_in,
                         float* __restrict__ drv) {
    int bh = blockIdx.x;            // 0..319
    int b = bh & 7, h = bh >> 3;
    int dst = (b * H_ + h) * N_;
    for (int i = threadIdx.x; i < N_; i += blockDim.x) {
        float u  = input[i * (H_ * B_N) + h * B_N + b];
        float nz = noise_in[i * (H_ * B_N) + h * B_N + b];
        drv[dst + i] = 325.0f * (5.0f * u + 100.0f * nz + 0.5f);
    }
}

// k1: per-row i: ws row (symmetric log1p), row-sum, sum-of-squares, ring init,
//     and deterministic (ascending-j) sparse list of {j : delays[j,i]==0},
//     layout [k][i], padded to SMAX with (j=i, w=0).
__global__ void k1_prep(const float* __restrict__ wbb, const float* __restrict__ sc,
                        const float* __restrict__ hE_in, const int* __restrict__ delays,
                        float* __restrict__ ws, float* __restrict__ ring,
                        float* __restrict__ rowsum_ws, float* __restrict__ sumsq,
                        float* __restrict__ s0w, int* __restrict__ s0j, int* __restrict__ s0c) {
    int i = blockIdx.x;
    int t = threadIdx.x;            // 256 threads
    __shared__ float wsrow[N_];
    __shared__ float red[256];
    __shared__ int cnt_c[8];
    __shared__ int cnt_base[8];

    // pad init (ordering vs fill guaranteed by the reduce barriers below)
    if (t < SMAX) { s0j[t * N_ + i] = i; s0w[t * N_ + i] = 0.f; }

    float ssq = 0.f, rsum = 0.f;
    for (int j = t; j < N_; j += 256) {
        float w = 0.5f * (expf(wbb[i * N_ + j]) * sc[i * N_ + j] +
                          expf(wbb[j * N_ + i]) * sc[j * N_ + i]);
        float v = log1pf(w);
        ws[i * N_ + j] = v;
        wsrow[j] = v;
        ssq += v * v;
        rsum += v;
    }
    // ring init: slots 8..391 = hE_in cols 0..383
    for (int k = t; k < D_; k += 256) ring[i * RW + 8 + k] = hE_in[i * D_ + k];

    red[t] = ssq; __syncthreads();
    for (int s = 128; s > 0; s >>= 1) { if (t < s) red[t] += red[t + s]; __syncthreads(); }
    if (t == 0) sumsq[i] = red[0];
    __syncthreads();
    red[t] = rsum; __syncthreads();
    for (int s = 128; s > 0; s >>= 1) { if (t < s) red[t] += red[t + s]; __syncthreads(); }
    if (t == 0) rowsum_ws[i] = red[0];
    __syncthreads();

    // sparse build: j = t (chunks 0..3), j = t+256 (chunks 4..7); wave ballots keep j order
    int wave = t >> 6, lane = t & 63;
    bool f1 = (delays[t * N_ + i] == 0);
    bool f2 = (delays[(t + 256) * N_ + i] == 0);
    unsigned long long m1 = __ballot(f1);
    unsigned long long m2 = __ballot(f2);
    if (lane == 0) { cnt_c[wave] = __popcll(m1); cnt_c[wave + 4] = __popcll(m2); }
    __syncthreads();
    if (t == 0) {
        int s = 0;
        for (int c = 0; c < 8; c++) { cnt_base[c] = s; s += cnt_c[c]; }
        s0c[i] = (s > SMAX) ? SMAX : s;
    }
    __syncthreads();
    unsigned long long below = (lane == 0) ? 0ull : ((~0ull) >> (64 - lane));
    if (f1) {
        int pos = cnt_base[wave] + __popcll(m1 & below);
        if (pos < SMAX) { s0j[pos * N_ + i] = t;       s0w[pos * N_ + i] = wsrow[t]; }
    }
    if (f2) {
        int pos = cnt_base[wave + 4] + __popcll(m2 & below);
        if (pos < SMAX) { s0j[pos * N_ + i] = t + 256; s0w[pos * N_ + i] = wsrow[t + 256]; }
    }
}

// k2: reduce norm, scale rowsum + sparse weights, per-wave max count, init state (SoA)
__global__ void k2_finish(const float* __restrict__ hx, const float* __restrict__ sumsq,
                          const float* __restrict__ rowsum_ws, float* __restrict__ invn,
                          float* __restrict__ rowsum_n, float* __restrict__ s0w,
                          const int* __restrict__ s0c, int* __restrict__ wmaxc,
                          float* __restrict__ state) {
    __shared__ float red[N_];
    __shared__ float inv_s;
    int t = threadIdx.x;            // 512 threads
    red[t] = sumsq[t]; __syncthreads();
    for (int s = 256; s > 0; s >>= 1) { if (t < s) red[t] += red[t + s]; __syncthreads(); }
    if (t == 0) { float iv = 1.0f / sqrtf(red[0]); invn[0] = iv; inv_s = iv; }
    __syncthreads();
    float iv = inv_s;
    rowsum_n[t] = rowsum_ws[t] * iv;
    for (int k = 0; k < SMAX; k++) s0w[k * N_ + t] *= iv;   // padded entries are 0
    for (int cc = 0; cc < 6; cc++) state[cc * N_ + t] = hx[t * 6 + cc];
    // per-wave max sparse count (wave of k_hidden == nodes 64w..64w+63)
    int m = s0c[t];
    for (int off = 32; off > 0; off >>= 1) {
        int o = __shfl_xor(m, off, 64);
        m = (o > m) ? o : m;
    }
    if ((t & 63) == 0) wmaxc[t >> 6] = m;
}

// base_b[i] = sum_{j, d_ji>=1} ws[j,i] * ring[j, (8-b)+d_ji]   (unscaled; x invnorm in hidden)
// 64 blocks = 8 i-blocks x 8 j-blocks; partials written per j-block (no atomics).
__global__ void k_base(const float* __restrict__ ws, const int* __restrict__ delays,
                       const float* __restrict__ ring, float* __restrict__ bp, int b) {
    int ib = blockIdx.x >> 3, jb = blockIdx.x & 7;
    int wave = threadIdx.x >> 6, lane = threadIdx.x & 63;
    int i = ib * 64 + lane;
    int off = 8 - b;
    float acc = 0.f;
    int j0 = jb * 64 + wave * 16;
    for (int jj = 0; jj < 16; jj++) {
        int j = j0 + jj;
        int d = delays[j * N_ + i];          // coalesced
        float w = ws[j * N_ + i];            // coalesced (symmetric)
        float v = ring[j * RW + off + d];    // gather within one ring row (hot)
        if (d > 0) acc += w * v;
    }
    __shared__ float part[4][64];
    part[wave][lane] = acc; __syncthreads();
    if (wave == 0) {
        float s = part[0][lane] + part[1][lane] + part[2][lane] + part[3][lane];
        bp[jb * N_ + i] = s;
    }
}

#define LOADK(K) int j##K = s0j_g[K * N_ + i]; float w##K = s0w_g[K * N_ + i];
#define GATH(K)  float g##K = 0.f; if (wmax > K) g##K = cb[j##K];

// 40 hidden Euler steps for batch b; one WG, thread i = node i.
// Pipelined: curr[(h+1)&1] written from pre-update velocities BEFORE the
// gather result is consumed -> gather LDS latency overlaps local VALU work.
__global__ void __launch_bounds__(512)
k_hidden(const float* __restrict__ drv, const float* __restrict__ hE_in,
         const float* __restrict__ lm, const float* __restrict__ bp,
         const float* __restrict__ invn, const float* __restrict__ rowsum_n,
         const float* __restrict__ s0w_g, const int* __restrict__ s0j_g,
         const int* __restrict__ wmaxc, float* __restrict__ state,
         float* __restrict__ ring, float* __restrict__ out, int b) {
    __shared__ float curr[2][N_];
    int i = threadIdx.x;
    int wavei = i >> 6, lane = i & 63;

    int wmax = __builtin_amdgcn_readfirstlane(wmaxc[wavei]);

    // loop-invariant sparse lists -> registers (coalesced [k][i] loads)
    LOADK(0)  LOADK(1)  LOADK(2)  LOADK(3)  LOADK(4)  LOADK(5)  LOADK(6)
    LOADK(7)  LOADK(8)  LOADK(9)  LOADK(10) LOADK(11) LOADK(12)

    float M  = state[0 * N_ + i], E  = state[1 * N_ + i], I  = state[2 * N_ + i];
    float Mv = state[3 * N_ + i], Ev = state[4 * N_ + i], Iv = state[5 * N_ + i];
    float iv = invn[0];
    float base = 0.f;
#pragma unroll
    for (int p = 0; p < 8; p++) base += bp[p * N_ + i];
    base *= iv;
    float rs = rowsum_n[i];
    const float* dp = drv + (size_t)b * H_ * N_;
    float d_c = dp[i];

    // prologue: step-0 buffer (batch 0 step 0 reads the INPUT hE col 0)
    curr[0][i] = (b == 0) ? hE_in[i * D_] : (E - I);
    __syncthreads();

    for (int h = 0; h < H_; h++) {
        const float* cb = curr[h & 1];
        // issue all gather reads (independent, wave-uniform count -> scalar branches)
        GATH(0)  GATH(1)  GATH(2)  GATH(3)  GATH(4)  GATH(5)  GATH(6)
        GATH(7)  GATH(8)  GATH(9)  GATH(10) GATH(11) GATH(12)

        int hn = (h < H_ - 1) ? h + 1 : h;
        float d_n = dp[hn * N_ + i];

        float ei = E - I;
        float rM = 5.0f   / (1.0f + __expf(0.56f * (6.0f - ei)));
        float rE = 540.0f  / (1.0f + __expf(0.56f * (6.0f - 135.0f * M)));
        float rI = 168.75f / (1.0f + __expf(0.56f * (6.0f - 33.75f * M)));

        // position update uses PRE-update velocities -> next buffer writable now
        float Mn = M + 1e-4f * Mv;
        float En = E + 1e-4f * Ev;
        float In = I + 1e-4f * Iv;
        curr[(h + 1) & 1][i] = En - In;

        // consume gather
        float sp = w0 * g0;
        sp = fmaf(w1, g1, sp);   sp = fmaf(w2, g2, sp);   sp = fmaf(w3, g3, sp);
        sp = fmaf(w4, g4, sp);   sp = fmaf(w5, g5, sp);   sp = fmaf(w6, g6, sp);
        sp = fmaf(w7, g7, sp);   sp = fmaf(w8, g8, sp);   sp = fmaf(w9, g9, sp);
        sp = fmaf(w10, g10, sp); sp = fmaf(w11, g11, sp); sp = fmaf(w12, g12, sp);
        float LEd = base + sp;
        float coupled = 100.0f * (LEd - rs * ei);
        // 500*tanh(coupled/500) = 500*(1 - 2/(exp(coupled*0.004)+1)); saturates correctly
        float ex = __expf(coupled * 0.004f);
        float coupling = 500.0f * (1.0f - 2.0f / (ex + 1.0f));

        float Mvn = Mv + 1e-4f * (325.0f * rM - 200.0f * Mv - 10000.0f * M);
        float Evn = Ev + 1e-4f * (325.0f * (rE + coupling) + d_c - 200.0f * Ev - 10000.0f * E);
        float Ivn = Iv + 1e-4f * (1100.0f * rI - 100.0f * Iv - 2500.0f * I);
        M = Mn; E = En; I = In; Mv = Mvn; Ev = Evn; Iv = Ivn;
        d_c = d_n;
        __syncthreads();
    }

    float eif = E - I;
    out[OUT_ES  + i * B_N + b] = E;
    out[OUT_IS  + i * B_N + b] = I;
    out[OUT_MS  + i * B_N + b] = M;
    out[OUT_EVS + i * B_N + b] = Ev;
    out[OUT_IVS + i * B_N + b] = Iv;
    out[OUT_MVS + i * B_N + b] = Mv;
    ring[i * RW + (7 - b)] = eif;            // new col 0 after shift
    ring[i * RW + (8 - b)] = eif;            // old col 0's final (live) value
    state[0 * N_ + i] = M;  state[1 * N_ + i] = E;  state[2 * N_ + i] = I;
    state[3 * N_ + i] = Mv; state[4 * N_ + i] = Ev; state[5 * N_ + i] = Iv;
    if (b == B_N - 1) {
        out[i * 6 + 0] = M;  out[i * 6 + 1] = E;  out[i * 6 + 2] = I;
        out[i * 6 + 3] = Mv; out[i * 6 + 4] = Ev; out[i * 6 + 5] = Iv;
    }

    // eeg = 0.0005 * lm @ (E-I): 8 waves x rows, shuffle-reduce
    curr[0][i] = eif;
    __syncthreads();
    for (int o = wavei; o < O_; o += 8) {
        float p = 0.f;
#pragma unroll
        for (int m = 0; m < 8; m++) {
            int idx = lane + 64 * m;
            p += lm[o * N_ + idx] * curr[0][idx];
        }
        for (int off2 = 32; off2 > 0; off2 >>= 1) p += __shfl_down(p, off2, 64);
        if (lane == 0) out[OUT_EEG + o * B_N + b] = 0.0005f * p;
    }
}

__global__ void k_final(const float* __restrict__ ring, float* __restrict__ out) {
    int i = blockIdx.x;
    for (int k = threadIdx.x; k < D_; k += 256)
        out[OUT_HE + i * D_ + k] = ring[i * RW + k];
}

extern "C" void kernel_launch(void* const* d_in, const int* in_sizes, int n_in,
                              void* d_out, int out_size, void* d_ws, size_t ws_size,
                              hipStream_t stream) {
    const float* input    = (const float*)d_in[0];
    const float* noise_in = (const float*)d_in[1];
    // d_in[2] = noise_out: unused by the reference
    const float* hx       = (const float*)d_in[3];
    const float* hE       = (const float*)d_in[4];
    const float* wbb      = (const float*)d_in[5];
    const float* sc       = (const float*)d_in[6];
    const float* lm       = (const float*)d_in[7];
    const int*   delays   = (const int*)d_in[8];
    float* out = (float*)d_out;

    // workspace carve-up (floats)
    float* F    = (float*)d_ws;
    float* drv  = F;                      // 163840
    float* wsm  = drv + 163840;           // 262144
    float* ring = wsm + 262144;           // 200704 (512 x 392)
    float* bp   = ring + 200704;          // 4096   (8 x 512 partials)
    float* rsw  = bp + 4096;              // 512
    float* ssq  = rsw + 512;              // 512
    float* invn = ssq + 512;              // 8
    float* rsn  = invn + 8;               // 512
    float* s0w  = rsn + 512;              // 512*13 ([k][i])
    int*   s0j  = (int*)(s0w + N_ * SMAX);// 512*13 ([k][i])
    int*   s0c  = s0j + N_ * SMAX;        // 512
    int*   wmaxc = s0c + N_;              // 8
    float* state = (float*)(wmaxc + 8);   // 3072

    k0_drive<<<H_ * B_N, 256, 0, stream>>>(input, noise_in, drv);
    k1_prep<<<N_, 256, 0, stream>>>(wbb, sc, hE, delays, wsm, ring, rsw, ssq, s0w, s0j, s0c);
    k2_finish<<<1, N_, 0, stream>>>(hx, ssq, rsw, invn, rsn, s0w, s0c, wmaxc, state);
    for (int b = 0; b < B_N; b++) {
        k_base<<<64, 256, 0, stream>>>(wsm, delays, ring, bp, b);
        k_hidden<<<1, N_, 0, stream>>>(drv, hE, lm, bp, invn, rsn,
                                       s0w, s0j, wmaxc, state, ring, out, b);
    }
    k_final<<<N_, 256, 0, stream>>>(ring, out);
}

// Round 3
// 182.457 us; speedup vs baseline: 2.2259x; 1.7843x over previous
//
#include <hip/hip_runtime.h>
#include <math.h>

#define N_    512
#define H_    40
#define B_N   8
#define D_    384
#define O_    62
#define RW    392     // ring width: D + 8 batch shifts
#define SMAX  13      // cap on delay==0 entries per column (E[cnt]=1.33)

// ---- output flat offsets (f32 elements, reference return order) ----
#define OUT_STATE 0        // (N,6)   3072
#define OUT_EEG   3072     // (O,B)   496
#define OUT_ES    3568     // (N,B)   4096
#define OUT_IS    7664
#define OUT_MS    11760
#define OUT_EVS   15856
#define OUT_IVS   19952
#define OUT_MVS   24048
#define OUT_HE    28144    // (N,D)   196608

// folded constants
#define LOG2E     1.4426950408889634f
#define SIGK      0.8079092228978195f    // 0.56*log2e
#define SIGC      4.847455337386917f     // 6*0.56*log2e
#define SIGK_E    109.06774509120563f    // SIGK*135
#define SIGK_I    27.266936272801407f    // SIGK*33.75
#define TANHS     0.5770780163555854f    // 100*0.004*log2e (pre-invnorm scale)

// k_prep: merged drive-fuse (blocks<320) + per-row connectome prep (all 512 blocks)
__global__ void k_prep(const float* __restrict__ input, const float* __restrict__ noise_in,
                       float* __restrict__ drv,
                       const float* __restrict__ wbb, const float* __restrict__ sc,
                       const float* __restrict__ hE_in, const int* __restrict__ delays,
                       float* __restrict__ ws, float* __restrict__ ring,
                       float* __restrict__ rowsum_ws, float* __restrict__ sumsq,
                       float* __restrict__ s0w, int* __restrict__ s0j, int* __restrict__ s0c) {
    int i = blockIdx.x;
    int t = threadIdx.x;            // 256 threads
    __shared__ float wsrow[N_];
    __shared__ float red[256];
    __shared__ int cnt_c[8];
    __shared__ int cnt_base[8];

    // drive: drv = 1e-4*325*(5u+100nz+0.5) + 16.25  (tanh const pre-added)
    if (i < H_ * B_N) {
        int b = i & 7, h = i >> 3;
        int dst = (b * H_ + h) * N_;
        for (int n = t; n < N_; n += 256) {
            float u  = input[n * (H_ * B_N) + h * B_N + b];
            float nz = noise_in[n * (H_ * B_N) + h * B_N + b];
            drv[dst + n] = fmaf(0.1625f, u, fmaf(3.25f, nz, 16.26625f));
        }
    }

    // pad sparse lists (ordering vs fill guaranteed by the reduce barriers below)
    if (t < SMAX) { s0j[t * N_ + i] = i; s0w[t * N_ + i] = 0.f; }

    float ssq = 0.f, rsum = 0.f;
    for (int j = t; j < N_; j += 256) {
        float w = 0.5f * (expf(wbb[i * N_ + j]) * sc[i * N_ + j] +
                          expf(wbb[j * N_ + i]) * sc[j * N_ + i]);
        float v = log1pf(w);
        ws[i * N_ + j] = v;
        wsrow[j] = v;
        ssq += v * v;
        rsum += v;
    }
    // ring init: slots 8..391 = hE_in cols 0..383
    for (int k = t; k < D_; k += 256) ring[i * RW + 8 + k] = hE_in[i * D_ + k];

    red[t] = ssq; __syncthreads();
    for (int s = 128; s > 0; s >>= 1) { if (t < s) red[t] += red[t + s]; __syncthreads(); }
    if (t == 0) sumsq[i] = red[0];
    __syncthreads();
    red[t] = rsum; __syncthreads();
    for (int s = 128; s > 0; s >>= 1) { if (t < s) red[t] += red[t + s]; __syncthreads(); }
    if (t == 0) rowsum_ws[i] = red[0];
    __syncthreads();

    // sparse build: j = t (chunks 0..3), j = t+256 (chunks 4..7); wave ballots keep j order
    int wave = t >> 6, lane = t & 63;
    bool f1 = (delays[t * N_ + i] == 0);
    bool f2 = (delays[(t + 256) * N_ + i] == 0);
    unsigned long long m1 = __ballot(f1);
    unsigned long long m2 = __ballot(f2);
    if (lane == 0) { cnt_c[wave] = __popcll(m1); cnt_c[wave + 4] = __popcll(m2); }
    __syncthreads();
    if (t == 0) {
        int s = 0;
        for (int c = 0; c < 8; c++) { cnt_base[c] = s; s += cnt_c[c]; }
        s0c[i] = (s > SMAX) ? SMAX : s;
    }
    __syncthreads();
    unsigned long long below = (lane == 0) ? 0ull : ((~0ull) >> (64 - lane));
    if (f1) {
        int pos = cnt_base[wave] + __popcll(m1 & below);
        if (pos < SMAX) { s0j[pos * N_ + i] = t;       s0w[pos * N_ + i] = wsrow[t]; }
    }
    if (f2) {
        int pos = cnt_base[wave + 4] + __popcll(m2 & below);
        if (pos < SMAX) { s0j[pos * N_ + i] = t + 256; s0w[pos * N_ + i] = wsrow[t + 256]; }
    }
}

// base_b[i] = sum_{j, d_ji>=1} ws[j,i] * ring[j, (8-b)+d_ji]   (unscaled)
// 64 blocks = 8 i-blocks x 8 j-blocks; 512 thr = 64 i x 8 j-waves, 8 j/thread.
__global__ void __launch_bounds__(512)
k_base(const float* __restrict__ ws, const int* __restrict__ delays,
       const float* __restrict__ ring, float* __restrict__ bp, int b) {
    int ib = blockIdx.x >> 3, jb = blockIdx.x & 7;
    int wave = threadIdx.x >> 6, lane = threadIdx.x & 63;
    int i = ib * 64 + lane;
    int off = 8 - b;
    float acc = 0.f;
    int j0 = jb * 64 + wave * 8;
#pragma unroll
    for (int jj = 0; jj < 8; jj++) {
        int j = j0 + jj;
        int d = delays[j * N_ + i];          // coalesced
        float w = ws[j * N_ + i];            // coalesced (symmetric)
        float v = ring[j * RW + off + d];    // gather within one ring row
        acc += (d > 0 ? w : 0.f) * v;
    }
    __shared__ float part[8][64];
    part[wave][lane] = acc; __syncthreads();
    if (wave == 0) {
        float s = 0.f;
#pragma unroll
        for (int w2 = 0; w2 < 8; w2++) s += part[w2][lane];
        bp[jb * N_ + i] = s;
    }
}

#define LOADK(K) int j##K = s0j_g[K * N_ + i]; float w##K = s0w_g[K * N_ + i] * scale;

// 40 hidden Euler steps for batch b; one WG, thread i = node i.
__global__ void __launch_bounds__(512)
k_hidden(const float* __restrict__ drv, const float* __restrict__ hE_in,
         const float* __restrict__ hx, const float* __restrict__ bp,
         const float* __restrict__ sumsq, const float* __restrict__ rowsum_ws,
         const float* __restrict__ s0w_g, const int* __restrict__ s0j_g,
         const int* __restrict__ s0c, float* __restrict__ state,
         float* __restrict__ ring, float* __restrict__ eegsrc,
         float* __restrict__ out, int b) {
    __shared__ float curr[2][N_];
    __shared__ float red[N_];
    int i = threadIdx.x;

    // per-wave max sparse count -> SGPR
    int cnt = s0c[i];
    int m = cnt;
#pragma unroll
    for (int off = 32; off > 0; off >>= 1) {
        int o = __shfl_xor(m, off, 64);
        m = (o > m) ? o : m;
    }
    int wmax = __builtin_amdgcn_readfirstlane(m);

    // norm reduce: scale = TANHS / ||ws||
    red[i] = sumsq[i];
    __syncthreads();
    if (i < 64) {
        float s2 = 0.f;
#pragma unroll
        for (int q = 0; q < 8; q++) s2 += red[i + 64 * q];
#pragma unroll
        for (int off = 32; off > 0; off >>= 1) s2 += __shfl_xor(s2, off, 64);
        if (i == 0) red[0] = s2;
    }
    __syncthreads();
    float scale = TANHS / sqrtf(red[0]);

    // loop-invariant sparse lists -> registers (coalesced [k][i] loads), prescaled
    LOADK(0)  LOADK(1)  LOADK(2)  LOADK(3)  LOADK(4)  LOADK(5)  LOADK(6)
    LOADK(7)  LOADK(8)  LOADK(9)  LOADK(10) LOADK(11) LOADK(12)

    float M, E, I, Mv, Ev, Iv;
    if (b == 0) {
        M  = hx[i * 6 + 0]; E  = hx[i * 6 + 1]; I  = hx[i * 6 + 2];
        Mv = hx[i * 6 + 3]; Ev = hx[i * 6 + 4]; Iv = hx[i * 6 + 5];
    } else {
        M  = state[0 * N_ + i]; E  = state[1 * N_ + i]; I  = state[2 * N_ + i];
        Mv = state[3 * N_ + i]; Ev = state[4 * N_ + i]; Iv = state[5 * N_ + i];
    }
    float base = 0.f;
#pragma unroll
    for (int p = 0; p < 8; p++) base += bp[p * N_ + i];
    base *= scale;                            // pre-scaled exp2 argument part
    float rs = rowsum_ws[i] * scale;
    const float* dp = drv + (size_t)b * H_ * N_;
    float d_c = dp[i];

    curr[0][i] = (b == 0) ? hE_in[i * D_] : (E - I);
    __syncthreads();

#pragma unroll 2
    for (int h = 0; h < H_; h++) {
        const float* cb = curr[h & 1];
        // gathers: first 8 unconditional (padded lists), rest behind one uniform branch
        float g0 = cb[j0], g1 = cb[j1], g2 = cb[j2], g3 = cb[j3];
        float g4 = cb[j4], g5 = cb[j5], g6 = cb[j6], g7 = cb[j7];
        float g8 = 0.f, g9 = 0.f, g10 = 0.f, g11 = 0.f, g12 = 0.f;
        if (wmax > 8) { g8 = cb[j8]; g9 = cb[j9]; g10 = cb[j10]; g11 = cb[j11]; g12 = cb[j12]; }

        int hn = (h < H_ - 1) ? h + 1 : h;
        float d_n = dp[hn * N_ + i];

        // positions use pre-update velocities -> next buffer writable immediately
        float En = fmaf(1e-4f, Ev, E);
        float In = fmaf(1e-4f, Iv, I);
        float Mn = fmaf(1e-4f, Mv, M);
        curr[(h + 1) & 1][i] = En - In;

        float ei = E - I;
        // sigmoids via exp2+rcp (constants folded)
        float rMr = __builtin_amdgcn_rcpf(1.0f + __builtin_amdgcn_exp2f(fmaf(-SIGK,   ei, SIGC)));
        float rEr = __builtin_amdgcn_rcpf(1.0f + __builtin_amdgcn_exp2f(fmaf(-SIGK_E, M,  SIGC)));
        float rIr = __builtin_amdgcn_rcpf(1.0f + __builtin_amdgcn_exp2f(fmaf(-SIGK_I, M,  SIGC)));

        float Mvn = fmaf(0.1625f,  rMr, fmaf(0.98f, Mv, -M));
        float Ivn = fmaf(18.5625f, rIr, fmaf(0.99f, Iv, -0.25f * I));
        float pre = fmaf(17.55f,   rEr, fmaf(0.98f, Ev, -E) + d_c);
        float barg = fmaf(-rs, ei, base);

        // coupling: 325*500*tanh(...) folded -> 162500(in d_c) - 325000*rcp(1+exp2(arg))
        float p0 = fmaf(w0, g0, w1 * g1);
        float p1 = fmaf(w2, g2, w3 * g3);
        float p2 = fmaf(w4, g4, w5 * g5);
        float p3 = fmaf(w6, g6, w7 * g7);
        float p4 = fmaf(w8, g8, w9 * g9);
        float p5 = fmaf(w10, g10, w11 * g11);
        float p6 = fmaf(w12, g12, barg);
        float arg = ((p0 + p1) + (p2 + p3)) + ((p4 + p5) + p6);
        float cr = __builtin_amdgcn_rcpf(1.0f + __builtin_amdgcn_exp2f(arg));
        float Evn = fmaf(-32.5f, cr, pre);

        M = Mn; E = En; I = In; Mv = Mvn; Ev = Evn; Iv = Ivn;
        d_c = d_n;
        __syncthreads();
    }

    float eif = E - I;
    out[OUT_ES  + i * B_N + b] = E;
    out[OUT_IS  + i * B_N + b] = I;
    out[OUT_MS  + i * B_N + b] = M;
    out[OUT_EVS + i * B_N + b] = Ev;
    out[OUT_IVS + i * B_N + b] = Iv;
    out[OUT_MVS + i * B_N + b] = Mv;
    ring[i * RW + (7 - b)] = eif;            // new col 0 after shift
    ring[i * RW + (8 - b)] = eif;            // old col 0's final (live) value
    eegsrc[b * N_ + i] = eif;
    state[0 * N_ + i] = M;  state[1 * N_ + i] = E;  state[2 * N_ + i] = I;
    state[3 * N_ + i] = Mv; state[4 * N_ + i] = Ev; state[5 * N_ + i] = Iv;
    if (b == B_N - 1) {
        out[i * 6 + 0] = M;  out[i * 6 + 1] = E;  out[i * 6 + 2] = I;
        out[i * 6 + 3] = Mv; out[i * 6 + 4] = Ev; out[i * 6 + 5] = Iv;
    }
}

// k_post: blocks 0..511 copy final hE; blocks 512..573 compute eeg rows.
__global__ void k_post(const float* __restrict__ ring, const float* __restrict__ eegsrc,
                       const float* __restrict__ lm, float* __restrict__ out) {
    int bi = blockIdx.x;
    int lane = threadIdx.x;        // 64 threads
    if (bi < N_) {
#pragma unroll
        for (int q = 0; q < 6; q++) {
            int k = lane + 64 * q;
            if (k < D_) out[OUT_HE + bi * D_ + k] = ring[bi * RW + k];
        }
    } else {
        int o = bi - N_;
        float lv[8];
#pragma unroll
        for (int q = 0; q < 8; q++) lv[q] = lm[o * N_ + 64 * q + lane];
        for (int b = 0; b < B_N; b++) {
            float p = 0.f;
#pragma unroll
            for (int q = 0; q < 8; q++) p = fmaf(lv[q], eegsrc[b * N_ + 64 * q + lane], p);
#pragma unroll
            for (int off = 32; off > 0; off >>= 1) p += __shfl_down(p, off, 64);
            if (lane == 0) out[OUT_EEG + o * B_N + b] = 0.0005f * p;
        }
    }
}

extern "C" void kernel_launch(void* const* d_in, const int* in_sizes, int n_in,
                              void* d_out, int out_size, void* d_ws, size_t ws_size,
                              hipStream_t stream) {
    const float* input    = (const float*)d_in[0];
    const float* noise_in = (const float*)d_in[1];
    // d_in[2] = noise_out: unused by the reference
    const float* hx       = (const float*)d_in[3];
    const float* hE       = (const float*)d_in[4];
    const float* wbb      = (const float*)d_in[5];
    const float* sc       = (const float*)d_in[6];
    const float* lm       = (const float*)d_in[7];
    const int*   delays   = (const int*)d_in[8];
    float* out = (float*)d_out;

    // workspace carve-up (floats)
    float* F    = (float*)d_ws;
    float* drv  = F;                      // 163840
    float* wsm  = drv + 163840;           // 262144
    float* ring = wsm + 262144;           // 200704 (512 x 392)
    float* bp   = ring + 200704;          // 4096   (8 x 512 partials)
    float* rsw  = bp + 4096;              // 512
    float* ssq  = rsw + 512;              // 512
    float* s0w  = ssq + 512;              // 512*13 ([k][i])
    int*   s0j  = (int*)(s0w + N_ * SMAX);// 512*13 ([k][i])
    int*   s0c  = s0j + N_ * SMAX;        // 512
    float* state = (float*)(s0c + N_);    // 3072
    float* eegsrc = state + 3072;         // 4096 (8 x 512)

    k_prep<<<N_, 256, 0, stream>>>(input, noise_in, drv, wbb, sc, hE, delays,
                                   wsm, ring, rsw, ssq, s0w, s0j, s0c);
    for (int b = 0; b < B_N; b++) {
        k_base<<<64, 512, 0, stream>>>(wsm, delays, ring, bp, b);
        k_hidden<<<1, N_, 0, stream>>>(drv, hE, hx, bp, ssq, rsw,
                                       s0w, s0j, s0c, state, ring, eegsrc, out, b);
    }
    k_post<<<N_ + O_, 64, 0, stream>>>(ring, eegsrc, lm, out);
}

// Round 4
// 133.229 us; speedup vs baseline: 3.0484x; 1.3695x over previous
//
#include <hip/hip_runtime.h>
#include <math.h>

#define N_    512
#define H_    40
#define B_N   8
#define D_    384
#define O_    62
#define RW    392     // ring width: 8 batch slots + 384 history
#define SMAX  13      // cap: delay==0 entries per column (mean 1.33)
#define CMAX  28      // cap: delay in 1..7 entries per column (mean 9.33)

// ---- output flat offsets (f32 elements, reference return order) ----
#define OUT_STATE 0        // (N,6)   3072
#define OUT_EEG   3072     // (O,B)   496
#define OUT_ES    3568     // (N,B)   4096
#define OUT_IS    7664
#define OUT_MS    11760
#define OUT_EVS   15856
#define OUT_IVS   19952
#define OUT_MVS   24048
#define OUT_HE    28144    // (N,D)   196608

// folded constants
#define SIGK      0.8079092228978195f    // 0.56*log2e
#define SIGC      4.847455337386917f     // 6*0.56*log2e
#define SIGK_E    109.06774509120563f    // SIGK*135
#define SIGK_I    27.266936272801407f    // SIGK*33.75
#define TANHS     0.5770780163555854f    // 100*0.004*log2e (pre-invnorm scale)

// k_prep: drive fuse (blocks<320) + per-row connectome prep + sparse lists d=0 and d=1..7
__global__ void k_prep(const float* __restrict__ input, const float* __restrict__ noise_in,
                       float* __restrict__ drv,
                       const float* __restrict__ wbb, const float* __restrict__ sc,
                       const float* __restrict__ hE_in, const int* __restrict__ delays,
                       float* __restrict__ ws, float* __restrict__ ring,
                       float* __restrict__ rowsum_ws, float* __restrict__ sumsq,
                       float* __restrict__ s0w, int* __restrict__ s0j, int* __restrict__ s0c,
                       float* __restrict__ s1w, int* __restrict__ s1p) {
    int i = blockIdx.x;
    int t = threadIdx.x;            // 256 threads
    __shared__ float wsrow[N_];
    __shared__ float red[256];
    __shared__ int cnt_c[8];
    __shared__ int bases[8];
    __shared__ int runbase;

    // drive: drv = 1e-4*325*(5u+100nz+0.5) + 16.25 (tanh const pre-added)
    if (i < H_ * B_N) {
        int b = i & 7, h = i >> 3;
        int dst = (b * H_ + h) * N_;
        for (int n = t; n < N_; n += 256) {
            float u  = input[n * (H_ * B_N) + h * B_N + b];
            float nz = noise_in[n * (H_ * B_N) + h * B_N + b];
            drv[dst + n] = fmaf(0.1625f, u, fmaf(3.25f, nz, 16.26625f));
        }
    }

    // pads (ordering vs real writes guaranteed by reduce barriers below)
    if (t < SMAX) { s0j[t * N_ + i] = i;        s0w[t * N_ + i] = 0.f; }
    if (t < CMAX) { s1p[t * N_ + i] = (1 << 9); s1w[t * N_ + i] = 0.f; }
    if (t < 9)    { ring[i * RW + t] = 0.f; }   // slots 0..8 zero (recent-final slots)

    float ssq = 0.f, rsum = 0.f;
    for (int j = t; j < N_; j += 256) {
        float w = 0.5f * (expf(wbb[i * N_ + j]) * sc[i * N_ + j] +
                          expf(wbb[j * N_ + i]) * sc[j * N_ + i]);
        float v = log1pf(w);
        ws[i * N_ + j] = v;
        wsrow[j] = v;
        ssq += v * v;
        rsum += v;
    }
    // ring init: slots 9..391 = hE_in cols 1..383 (col 0 lives in LDS during batch 0)
    for (int k = t; k < D_ - 1; k += 256) ring[i * RW + 9 + k] = hE_in[i * D_ + 1 + k];

    red[t] = ssq; __syncthreads();
    for (int s = 128; s > 0; s >>= 1) { if (t < s) red[t] += red[t + s]; __syncthreads(); }
    if (t == 0) sumsq[i] = red[0];
    __syncthreads();
    red[t] = rsum; __syncthreads();
    for (int s = 128; s > 0; s >>= 1) { if (t < s) red[t] += red[t + s]; __syncthreads(); }
    if (t == 0) rowsum_ws[i] = red[0];
    __syncthreads();

    // sparse build, rounds d=0..7; j = t (chunks 0..3), j = t+256 (chunks 4..7)
    int wave = t >> 6, lane = t & 63;
    int dv1 = delays[t * N_ + i];
    int dv2 = delays[(t + 256) * N_ + i];
    unsigned long long below = (lane == 0) ? 0ull : ((~0ull) >> (64 - lane));
    for (int d = 0; d < 8; d++) {
        bool f1 = (dv1 == d), f2 = (dv2 == d);
        unsigned long long m1 = __ballot(f1);
        unsigned long long m2 = __ballot(f2);
        if (lane == 0) { cnt_c[wave] = __popcll(m1); cnt_c[wave + 4] = __popcll(m2); }
        __syncthreads();
        if (t == 0) {
            int s = (d == 0) ? 0 : runbase;
            for (int c = 0; c < 8; c++) { bases[c] = s; s += cnt_c[c]; }
            if (d == 0) { s0c[i] = (s > SMAX) ? SMAX : s; runbase = 0; }
            else runbase = s;
        }
        __syncthreads();
        if (d == 0) {
            if (f1) { int pos = bases[wave]     + __popcll(m1 & below);
                      if (pos < SMAX) { s0j[pos * N_ + i] = t;       s0w[pos * N_ + i] = wsrow[t]; } }
            if (f2) { int pos = bases[wave + 4] + __popcll(m2 & below);
                      if (pos < SMAX) { s0j[pos * N_ + i] = t + 256; s0w[pos * N_ + i] = wsrow[t + 256]; } }
        } else {
            if (f1) { int pos = bases[wave]     + __popcll(m1 & below);
                      if (pos < CMAX) { s1p[pos * N_ + i] = t | (d << 9);         s1w[pos * N_ + i] = wsrow[t]; } }
            if (f2) { int pos = bases[wave + 4] + __popcll(m2 & below);
                      if (pos < CMAX) { s1p[pos * N_ + i] = (t + 256) | (d << 9); s1w[pos * N_ + i] = wsrow[t + 256]; } }
        }
    }
}

// k_hist: hist partials for ALL batches upfront.
// hist_b[i] = sum_{j, d_ji > b} ws[j,i] * init_hist; slots 1..8 are zero, so (d>0) mask suffices.
// grid 512: b=blk>>6, ib=(blk>>3)&7, jb=blk&7; 512 thr = 64 i-lanes x 8 j-waves x 8 j each.
__global__ void __launch_bounds__(512)
k_hist(const float* __restrict__ ws, const int* __restrict__ delays,
       const float* __restrict__ ring, float* __restrict__ bp8) {
    int b  = blockIdx.x >> 6;
    int ib = (blockIdx.x >> 3) & 7;
    int jb = blockIdx.x & 7;
    int wave = threadIdx.x >> 6, lane = threadIdx.x & 63;
    int i = ib * 64 + lane;
    int off = 8 - b;
    float acc = 0.f;
    int j0 = jb * 64 + wave * 8;
#pragma unroll
    for (int jj = 0; jj < 8; jj++) {
        int j = j0 + jj;
        int d = delays[j * N_ + i];          // coalesced
        float w = ws[j * N_ + i];            // coalesced (symmetric)
        float v = ring[j * RW + off + d];    // gather within one ring row
        acc += (d > 0 ? w : 0.f) * v;        // d<=b terms read zeroed slots -> 0
    }
    __shared__ float part[8][64];
    part[wave][lane] = acc; __syncthreads();
    if (wave == 0) {
        float s = 0.f;
#pragma unroll
        for (int w2 = 0; w2 < 8; w2++) s += part[w2][lane];
        bp8[(b * 8 + jb) * N_ + i] = s;
    }
}

#define LOADK0(K) int jb_##K = s0j[K * N_ + i] << 2; float w_##K = s0w[K * N_ + i] * scale;
#define G(CB, K)  (*(const float*)((const char*)(CB) + jb_##K))

#define STEP(CB, CN)                                                           \
  {                                                                            \
    float g0 = G(CB,0), g1 = G(CB,1), g2 = G(CB,2);                            \
    float g3 = G(CB,3), g4 = G(CB,4), g5 = G(CB,5);                            \
    float g6=0.f,g7=0.f,g8=0.f,g9=0.f,g10=0.f,g11=0.f,g12=0.f;                 \
    if (wmax > 6) { g6=G(CB,6); g7=G(CB,7); g8=G(CB,8); g9=G(CB,9);            \
                    g10=G(CB,10); g11=G(CB,11); g12=G(CB,12); }                \
    float d_n = *dnext; dnext += N_;                                           \
    float En = fmaf(1e-4f, Ev, E);                                             \
    float In = fmaf(1e-4f, Iv, I);                                             \
    float Mn = fmaf(1e-4f, Mv, M);                                             \
    (CN)[i] = En - In;                                                         \
    float ei = E - I;                                                          \
    float rMr = __builtin_amdgcn_rcpf(1.0f + __builtin_amdgcn_exp2f(fmaf(-SIGK,   ei, SIGC))); \
    float rEr = __builtin_amdgcn_rcpf(1.0f + __builtin_amdgcn_exp2f(fmaf(-SIGK_E, M,  SIGC))); \
    float rIr = __builtin_amdgcn_rcpf(1.0f + __builtin_amdgcn_exp2f(fmaf(-SIGK_I, M,  SIGC))); \
    float Mvn = fmaf(0.1625f,  rMr, fmaf(0.98f, Mv, -M));                      \
    float Ivn = fmaf(18.5625f, rIr, fmaf(0.99f, Iv, -0.25f * I));              \
    float pre = fmaf(17.55f,   rEr, fmaf(0.98f, Ev, -E) + d_c);                \
    float p0 = fmaf(w_0, g0, w_1 * g1);                                        \
    float p1 = fmaf(w_2, g2, w_3 * g3);                                        \
    float p2 = fmaf(w_4, g4, w_5 * g5);                                        \
    float arg = (p0 + p1) + (p2 + fmaf(-rs, ei, base));                        \
    if (wmax > 6) {                                                            \
        arg += (fmaf(w_6, g6, w_7 * g7) + fmaf(w_8, g8, w_9 * g9)) +           \
               (fmaf(w_10, g10, w_11 * g11) + w_12 * g12);                     \
    }                                                                          \
    float cr = __builtin_amdgcn_rcpf(1.0f + __builtin_amdgcn_exp2f(arg));      \
    float Evn = fmaf(-32.5f, cr, pre);                                         \
    M = Mn; E = En; I = In; Mv = Mvn; Ev = Evn; Iv = Ivn; d_c = d_n;           \
    __syncthreads();                                                           \
  }

// ALL 8 batches x 40 steps in ONE kernel; one WG, thread i = node i.
__global__ void __launch_bounds__(512)
k_hidden(const float* __restrict__ drv, const float* __restrict__ hE_in,
         const float* __restrict__ hx, const float* __restrict__ bp8,
         const float* __restrict__ sumsq, const float* __restrict__ rowsum_ws,
         const float* __restrict__ s0w, const int* __restrict__ s0j,
         const int* __restrict__ s0c, const float* __restrict__ s1w,
         const int* __restrict__ s1p, float* __restrict__ ring,
         float* __restrict__ fing, float* __restrict__ out) {
    __shared__ float curr0[N_];
    __shared__ float curr1[N_];
    __shared__ float fin_l[B_N * N_];   // finals per batch (zero-init)
    __shared__ float red[N_];
    int i = threadIdx.x;

    // per-wave max of d0 count -> SGPR
    int m = s0c[i];
#pragma unroll
    for (int off = 32; off > 0; off >>= 1) {
        int o = __shfl_xor(m, off, 64);
        m = (o > m) ? o : m;
    }
    int wmax = __builtin_amdgcn_readfirstlane(m);

    // norm reduce: scale = TANHS / ||ws||
    red[i] = sumsq[i];
    __syncthreads();
    if (i < 64) {
        float s2 = 0.f;
#pragma unroll
        for (int q = 0; q < 8; q++) s2 += red[i + 64 * q];
#pragma unroll
        for (int off = 32; off > 0; off >>= 1) s2 += __shfl_xor(s2, off, 64);
        if (i == 0) red[0] = s2;
    }
    __syncthreads();
    float scale = TANHS / sqrtf(red[0]);

    // loop-invariant lists -> registers (coalesced [k][i] loads), prescaled
    LOADK0(0)  LOADK0(1)  LOADK0(2)  LOADK0(3)  LOADK0(4)  LOADK0(5)  LOADK0(6)
    LOADK0(7)  LOADK0(8)  LOADK0(9)  LOADK0(10) LOADK0(11) LOADK0(12)
    int   s1p_r[CMAX];
    float s1w_r[CMAX];
#pragma unroll
    for (int k = 0; k < CMAX; k++) { s1p_r[k] = s1p[k * N_ + i]; s1w_r[k] = s1w[k * N_ + i] * scale; }

    float M  = hx[i * 6 + 0], E  = hx[i * 6 + 1], I  = hx[i * 6 + 2];
    float Mv = hx[i * 6 + 3], Ev = hx[i * 6 + 4], Iv = hx[i * 6 + 5];
    float rs = rowsum_ws[i] * scale;

    // hist partials for batch 0
    float hp[8];
#pragma unroll
    for (int k = 0; k < 8; k++) hp[k] = bp8[k * N_ + i];

    const float* dnext = drv + i + N_;
    float d_c = drv[i];

    // zero the finals table; init live column for batch 0
    #pragma unroll
    for (int k = 0; k < B_N; k++) fin_l[k * N_ + i] = 0.f;
    curr0[i] = hE_in[i * D_];
    __syncthreads();

    for (int b = 0; b < B_N; b++) {
        // base_b = hist_b + correction from recent finals (unwritten slots are 0)
        float hist = (((hp[0] + hp[1]) + (hp[2] + hp[3])) +
                      ((hp[4] + hp[5]) + (hp[6] + hp[7]))) * scale;
        float corr = 0.f;
#pragma unroll
        for (int k = 0; k < CMAX; k++) {
            int p = s1p_r[k];
            int off = (((b + 8 - (p >> 9)) & 7) << 11) + ((p & 511) << 2);
            corr = fmaf(s1w_r[k], *(const float*)((const char*)fin_l + off), corr);
        }
        float base = hist + corr;

        // prefetch hist partials for next batch (hidden under 40 steps)
        int bn = (b < B_N - 1) ? b + 1 : b;
#pragma unroll
        for (int k = 0; k < 8; k++) hp[k] = bp8[(bn * 8 + k) * N_ + i];

        for (int hh = 0; hh < H_ / 2; hh++) {
            STEP(curr0, curr1)
            STEP(curr1, curr0)
        }
        // after 40 steps parity returns to curr0, which already holds E-I final
        float eif = E - I;
        fin_l[b * N_ + i] = eif;
        out[OUT_ES  + i * B_N + b] = E;
        out[OUT_IS  + i * B_N + b] = I;
        out[OUT_MS  + i * B_N + b] = M;
        out[OUT_EVS + i * B_N + b] = Ev;
        out[OUT_IVS + i * B_N + b] = Iv;
        out[OUT_MVS + i * B_N + b] = Mv;
        ring[i * RW + (7 - b)] = eif;        // new col 0 slot
        ring[i * RW + (8 - b)] = eif;        // old live slot's final value
        fing[b * N_ + i] = eif;
        __syncthreads();                     // fin_l visible for next batch's correction
    }

    out[i * 6 + 0] = M;  out[i * 6 + 1] = E;  out[i * 6 + 2] = I;
    out[i * 6 + 3] = Mv; out[i * 6 + 4] = Ev; out[i * 6 + 5] = Iv;
}

// k_post: blocks 0..511 copy final hE; blocks 512..573 compute eeg rows.
__global__ void k_post(const float* __restrict__ ring, const float* __restrict__ fing,
                       const float* __restrict__ lm, float* __restrict__ out) {
    int bi = blockIdx.x;
    int lane = threadIdx.x;        // 64 threads
    if (bi < N_) {
#pragma unroll
        for (int q = 0; q < 6; q++) {
            int k = lane + 64 * q;
            if (k < D_) out[OUT_HE + bi * D_ + k] = ring[bi * RW + k];
        }
    } else {
        int o = bi - N_;
        float lv[8];
#pragma unroll
        for (int q = 0; q < 8; q++) lv[q] = lm[o * N_ + 64 * q + lane];
        for (int b = 0; b < B_N; b++) {
            float p = 0.f;
#pragma unroll
            for (int q = 0; q < 8; q++) p = fmaf(lv[q], fing[b * N_ + 64 * q + lane], p);
#pragma unroll
            for (int off = 32; off > 0; off >>= 1) p += __shfl_down(p, off, 64);
            if (lane == 0) out[OUT_EEG + o * B_N + b] = 0.0005f * p;
        }
    }
}

extern "C" void kernel_launch(void* const* d_in, const int* in_sizes, int n_in,
                              void* d_out, int out_size, void* d_ws, size_t ws_size,
                              hipStream_t stream) {
    const float* input    = (const float*)d_in[0];
    const float* noise_in = (const float*)d_in[1];
    // d_in[2] = noise_out: unused by the reference
    const float* hx       = (const float*)d_in[3];
    const float* hE       = (const float*)d_in[4];
    const float* wbb      = (const float*)d_in[5];
    const float* sc       = (const float*)d_in[6];
    const float* lm       = (const float*)d_in[7];
    const int*   delays   = (const int*)d_in[8];
    float* out = (float*)d_out;

    // workspace carve-up (floats)
    float* F    = (float*)d_ws;
    float* drv  = F;                       // 321*512 = 164352 (row 320 = prefetch pad)
    float* wsm  = drv + 164352;            // 262144
    float* ring = wsm + 262144;            // 200704 (512 x 392)
    float* bp8  = ring + 200704;           // 32768  (8b x 8jb x 512)
    float* rsw  = bp8 + 32768;             // 512
    float* ssq  = rsw + 512;               // 512
    float* s0w  = ssq + 512;               // 13*512
    int*   s0j  = (int*)(s0w + N_ * SMAX); // 13*512
    int*   s0c  = s0j + N_ * SMAX;         // 512
    float* s1w  = (float*)(s0c + N_);      // 28*512
    int*   s1p  = (int*)(s1w + N_ * CMAX); // 28*512
    float* fing = (float*)(s1p + N_ * CMAX); // 8*512

    k_prep<<<N_, 256, 0, stream>>>(input, noise_in, drv, wbb, sc, hE, delays,
                                   wsm, ring, rsw, ssq, s0w, s0j, s0c, s1w, s1p);
    k_hist<<<512, 512, 0, stream>>>(wsm, delays, ring, bp8);
    k_hidden<<<1, N_, 0, stream>>>(drv, hE, hx, bp8, ssq, rsw,
                                   s0w, s0j, s0c, s1w, s1p, ring, fing, out);
    k_post<<<N_ + O_, 64, 0, stream>>>(ring, fing, lm, out);
}

// Round 5
// 133.017 us; speedup vs baseline: 3.0532x; 1.0016x over previous
//
#include <hip/hip_runtime.h>
#include <math.h>

#define N_    512
#define H_    40
#define B_N   8
#define D_    384
#define O_    62
#define RW    392     // ring width: 8 batch slots + 384 history
#define SMAX  13      // cap: delay==0 entries per column (mean 1.33)
#define CMAX  28      // cap: delay in 1..7 entries per column (mean 9.33)

// ---- output flat offsets (f32 elements, reference return order) ----
#define OUT_STATE 0        // (N,6)   3072
#define OUT_EEG   3072     // (O,B)   496
#define OUT_ES    3568     // (N,B)   4096
#define OUT_IS    7664
#define OUT_MS    11760
#define OUT_EVS   15856
#define OUT_IVS   19952
#define OUT_MVS   24048
#define OUT_HE    28144    // (N,D)   196608

// folded constants
#define SIGK      0.8079092228978195f    // 0.56*log2e
#define SIGC      4.847455337386917f     // 6*0.56*log2e
#define SIGK_E    109.06774509120563f    // SIGK*135
#define SIGK_I    27.266936272801407f    // SIGK*33.75
#define TANHS     0.5770780163555854f    // 100*0.004*log2e (pre-invnorm scale)

// LDS-only barrier: does NOT drain vmcnt -> global prefetches stay in flight
// across steps ("counted-vmcnt" principle). lgkmcnt(0) orders our ds_writes
// before the barrier; "memory" clobber pins LDS ops on their side of it.
#define BARRIER() asm volatile("s_waitcnt lgkmcnt(0)\n\ts_barrier" ::: "memory")

// k_prep: drive fuse (blocks<320) + per-row connectome prep + sparse lists d=0 and d=1..7
__global__ void k_prep(const float* __restrict__ input, const float* __restrict__ noise_in,
                       float* __restrict__ drv,
                       const float* __restrict__ wbb, const float* __restrict__ sc,
                       const float* __restrict__ hE_in, const int* __restrict__ delays,
                       float* __restrict__ ws, float* __restrict__ ring,
                       float* __restrict__ rowsum_ws, float* __restrict__ sumsq,
                       float* __restrict__ s0w, int* __restrict__ s0j, int* __restrict__ s0c,
                       float* __restrict__ s1w, int* __restrict__ s1p) {
    int i = blockIdx.x;
    int t = threadIdx.x;            // 256 threads
    __shared__ float wsrow[N_];
    __shared__ float red[256];
    __shared__ int cnt_c[8];
    __shared__ int bases[8];
    __shared__ int runbase;

    // drive: drv = 1e-4*325*(5u+100nz+0.5) + 16.25 (tanh const pre-added)
    if (i < H_ * B_N) {
        int b = i & 7, h = i >> 3;
        int dst = (b * H_ + h) * N_;
        for (int n = t; n < N_; n += 256) {
            float u  = input[n * (H_ * B_N) + h * B_N + b];
            float nz = noise_in[n * (H_ * B_N) + h * B_N + b];
            drv[dst + n] = fmaf(0.1625f, u, fmaf(3.25f, nz, 16.26625f));
        }
    }

    // pads (ordering vs real writes guaranteed by reduce barriers below)
    if (t < SMAX) { s0j[t * N_ + i] = i;        s0w[t * N_ + i] = 0.f; }
    if (t < CMAX) { s1p[t * N_ + i] = (1 << 9); s1w[t * N_ + i] = 0.f; }
    if (t < 9)    { ring[i * RW + t] = 0.f; }   // slots 0..8 zero (recent-final slots)

    float ssq = 0.f, rsum = 0.f;
    for (int j = t; j < N_; j += 256) {
        float w = 0.5f * (expf(wbb[i * N_ + j]) * sc[i * N_ + j] +
                          expf(wbb[j * N_ + i]) * sc[j * N_ + i]);
        float v = log1pf(w);
        ws[i * N_ + j] = v;
        wsrow[j] = v;
        ssq += v * v;
        rsum += v;
    }
    // ring init: slots 9..391 = hE_in cols 1..383 (col 0 lives in LDS during batch 0)
    for (int k = t; k < D_ - 1; k += 256) ring[i * RW + 9 + k] = hE_in[i * D_ + 1 + k];

    red[t] = ssq; __syncthreads();
    for (int s = 128; s > 0; s >>= 1) { if (t < s) red[t] += red[t + s]; __syncthreads(); }
    if (t == 0) sumsq[i] = red[0];
    __syncthreads();
    red[t] = rsum; __syncthreads();
    for (int s = 128; s > 0; s >>= 1) { if (t < s) red[t] += red[t + s]; __syncthreads(); }
    if (t == 0) rowsum_ws[i] = red[0];
    __syncthreads();

    // sparse build, rounds d=0..7; j = t (chunks 0..3), j = t+256 (chunks 4..7)
    int wave = t >> 6, lane = t & 63;
    int dv1 = delays[t * N_ + i];
    int dv2 = delays[(t + 256) * N_ + i];
    unsigned long long below = (lane == 0) ? 0ull : ((~0ull) >> (64 - lane));
    for (int d = 0; d < 8; d++) {
        bool f1 = (dv1 == d), f2 = (dv2 == d);
        unsigned long long m1 = __ballot(f1);
        unsigned long long m2 = __ballot(f2);
        if (lane == 0) { cnt_c[wave] = __popcll(m1); cnt_c[wave + 4] = __popcll(m2); }
        __syncthreads();
        if (t == 0) {
            int s = (d == 0) ? 0 : runbase;
            for (int c = 0; c < 8; c++) { bases[c] = s; s += cnt_c[c]; }
            if (d == 0) { s0c[i] = (s > SMAX) ? SMAX : s; runbase = 0; }
            else runbase = s;
        }
        __syncthreads();
        if (d == 0) {
            if (f1) { int pos = bases[wave]     + __popcll(m1 & below);
                      if (pos < SMAX) { s0j[pos * N_ + i] = t;       s0w[pos * N_ + i] = wsrow[t]; } }
            if (f2) { int pos = bases[wave + 4] + __popcll(m2 & below);
                      if (pos < SMAX) { s0j[pos * N_ + i] = t + 256; s0w[pos * N_ + i] = wsrow[t + 256]; } }
        } else {
            if (f1) { int pos = bases[wave]     + __popcll(m1 & below);
                      if (pos < CMAX) { s1p[pos * N_ + i] = t | (d << 9);         s1w[pos * N_ + i] = wsrow[t]; } }
            if (f2) { int pos = bases[wave + 4] + __popcll(m2 & below);
                      if (pos < CMAX) { s1p[pos * N_ + i] = (t + 256) | (d << 9); s1w[pos * N_ + i] = wsrow[t + 256]; } }
        }
    }
}

// k_hist: hist partials for ALL batches upfront.
// hist_b[i] = sum_{j, d_ji > b} ws[j,i] * init_hist; slots 1..8 are zero, so (d>0) mask suffices.
__global__ void __launch_bounds__(512)
k_hist(const float* __restrict__ ws, const int* __restrict__ delays,
       const float* __restrict__ ring, float* __restrict__ bp8) {
    int b  = blockIdx.x >> 6;
    int ib = (blockIdx.x >> 3) & 7;
    int jb = blockIdx.x & 7;
    int wave = threadIdx.x >> 6, lane = threadIdx.x & 63;
    int i = ib * 64 + lane;
    int off = 8 - b;
    float acc = 0.f;
    int j0 = jb * 64 + wave * 8;
#pragma unroll
    for (int jj = 0; jj < 8; jj++) {
        int j = j0 + jj;
        int d = delays[j * N_ + i];          // coalesced
        float w = ws[j * N_ + i];            // coalesced (symmetric)
        float v = ring[j * RW + off + d];    // gather within one ring row
        acc += (d > 0 ? w : 0.f) * v;        // d<=b terms read zeroed slots -> 0
    }
    __shared__ float part[8][64];
    part[wave][lane] = acc; __syncthreads();
    if (wave == 0) {
        float s = 0.f;
#pragma unroll
        for (int w2 = 0; w2 < 8; w2++) s += part[w2][lane];
        bp8[(b * 8 + jb) * N_ + i] = s;
    }
}

#define LOADK0(K) int jb_##K = s0j[K * N_ + i] << 2; float w_##K = s0w[K * N_ + i] * scale;
#define G(CB, K)  (*(const float*)((const char*)(CB) + jb_##K))

#define STEP(CB, CN)                                                           \
  {                                                                            \
    float g0 = G(CB,0), g1 = G(CB,1), g2 = G(CB,2);                            \
    float g3 = G(CB,3), g4 = G(CB,4), g5 = G(CB,5);                            \
    float g6=0.f,g7=0.f,g8=0.f,g9=0.f,g10=0.f,g11=0.f,g12=0.f;                 \
    if (wmax > 6) { g6=G(CB,6); g7=G(CB,7); g8=G(CB,8); g9=G(CB,9);            \
                    g10=G(CB,10); g11=G(CB,11); g12=G(CB,12); }                \
    float d_n = *dnext; dnext += N_;                                           \
    float En = fmaf(1e-4f, Ev, E);                                             \
    float In = fmaf(1e-4f, Iv, I);                                             \
    float Mn = fmaf(1e-4f, Mv, M);                                             \
    (CN)[i] = En - In;                                                         \
    float ei = E - I;                                                          \
    float rMr = __builtin_amdgcn_rcpf(1.0f + __builtin_amdgcn_exp2f(fmaf(-SIGK,   ei, SIGC))); \
    float rEr = __builtin_amdgcn_rcpf(1.0f + __builtin_amdgcn_exp2f(fmaf(-SIGK_E, M,  SIGC))); \
    float rIr = __builtin_amdgcn_rcpf(1.0f + __builtin_amdgcn_exp2f(fmaf(-SIGK_I, M,  SIGC))); \
    float Mvn = fmaf(0.1625f,  rMr, fmaf(0.98f, Mv, -M));                      \
    float Ivn = fmaf(18.5625f, rIr, fmaf(0.99f, Iv, -0.25f * I));              \
    float pre = fmaf(17.55f,   rEr, fmaf(0.98f, Ev, -E) + d_c);                \
    float p0 = fmaf(w_0, g0, w_1 * g1);                                        \
    float p1 = fmaf(w_2, g2, w_3 * g3);                                        \
    float p2 = fmaf(w_4, g4, w_5 * g5);                                        \
    float arg = (p0 + p1) + (p2 + fmaf(-rs, ei, base));                        \
    if (wmax > 6) {                                                            \
        arg += (fmaf(w_6, g6, w_7 * g7) + fmaf(w_8, g8, w_9 * g9)) +           \
               (fmaf(w_10, g10, w_11 * g11) + w_12 * g12);                     \
    }                                                                          \
    float cr = __builtin_amdgcn_rcpf(1.0f + __builtin_amdgcn_exp2f(arg));      \
    float Evn = fmaf(-32.5f, cr, pre);                                         \
    M = Mn; E = En; I = In; Mv = Mvn; Ev = Evn; Iv = Ivn; d_c = d_n;           \
    BARRIER();                                                                 \
  }

// ALL 8 batches x 40 steps in ONE kernel; one WG, thread i = node i.
__global__ void __launch_bounds__(512)
k_hidden(const float* __restrict__ drv, const float* __restrict__ hE_in,
         const float* __restrict__ hx, const float* __restrict__ bp8,
         const float* __restrict__ sumsq, const float* __restrict__ rowsum_ws,
         const float* __restrict__ s0w, const int* __restrict__ s0j,
         const int* __restrict__ s0c, const float* __restrict__ s1w,
         const int* __restrict__ s1p, float* __restrict__ ring,
         float* __restrict__ fing, float* __restrict__ out) {
    __shared__ float curr0[N_];
    __shared__ float curr1[N_];
    __shared__ float fin_l[B_N * N_];   // finals per batch (zero-init)
    __shared__ float red[N_];
    int i = threadIdx.x;

    // per-wave max of d0 count -> SGPR
    int m = s0c[i];
#pragma unroll
    for (int off = 32; off > 0; off >>= 1) {
        int o = __shfl_xor(m, off, 64);
        m = (o > m) ? o : m;
    }
    int wmax = __builtin_amdgcn_readfirstlane(m);

    // norm reduce: scale = TANHS / ||ws||
    red[i] = sumsq[i];
    __syncthreads();
    if (i < 64) {
        float s2 = 0.f;
#pragma unroll
        for (int q = 0; q < 8; q++) s2 += red[i + 64 * q];
#pragma unroll
        for (int off = 32; off > 0; off >>= 1) s2 += __shfl_xor(s2, off, 64);
        if (i == 0) red[0] = s2;
    }
    __syncthreads();
    float scale = TANHS / sqrtf(red[0]);

    // loop-invariant lists -> registers (coalesced [k][i] loads), prescaled
    LOADK0(0)  LOADK0(1)  LOADK0(2)  LOADK0(3)  LOADK0(4)  LOADK0(5)  LOADK0(6)
    LOADK0(7)  LOADK0(8)  LOADK0(9)  LOADK0(10) LOADK0(11) LOADK0(12)
    int   s1p_r[CMAX];
    float s1w_r[CMAX];
#pragma unroll
    for (int k = 0; k < CMAX; k++) { s1p_r[k] = s1p[k * N_ + i]; s1w_r[k] = s1w[k * N_ + i] * scale; }

    float M  = hx[i * 6 + 0], E  = hx[i * 6 + 1], I  = hx[i * 6 + 2];
    float Mv = hx[i * 6 + 3], Ev = hx[i * 6 + 4], Iv = hx[i * 6 + 5];
    float rs = rowsum_ws[i] * scale;

    // hist partials for batch 0
    float hp[8];
#pragma unroll
    for (int k = 0; k < 8; k++) hp[k] = bp8[k * N_ + i];

    const float* dnext = drv + i + N_;
    float d_c = drv[i];

    // zero the finals table; init live column for batch 0
    #pragma unroll
    for (int k = 0; k < B_N; k++) fin_l[k * N_ + i] = 0.f;
    curr0[i] = hE_in[i * D_];
    __syncthreads();

    for (int b = 0; b < B_N; b++) {
        // base_b = hist_b + correction from recent finals (unwritten slots are 0)
        float hist = (((hp[0] + hp[1]) + (hp[2] + hp[3])) +
                      ((hp[4] + hp[5]) + (hp[6] + hp[7]))) * scale;
        float corr = 0.f;
#pragma unroll
        for (int k = 0; k < CMAX; k++) {
            int p = s1p_r[k];
            int off = (((b + 8 - (p >> 9)) & 7) << 11) + ((p & 511) << 2);
            corr = fmaf(s1w_r[k], *(const float*)((const char*)fin_l + off), corr);
        }
        float base = hist + corr;

        // prefetch hist partials for next batch (hidden under 40 steps)
        int bn = (b < B_N - 1) ? b + 1 : b;
#pragma unroll
        for (int k = 0; k < 8; k++) hp[k] = bp8[(bn * 8 + k) * N_ + i];

        for (int hh = 0; hh < H_ / 2; hh++) {
            STEP(curr0, curr1)
            STEP(curr1, curr0)
        }
        // after 40 steps parity returns to curr0, which already holds E-I final
        float eif = E - I;
        fin_l[b * N_ + i] = eif;
        out[OUT_ES  + i * B_N + b] = E;
        out[OUT_IS  + i * B_N + b] = I;
        out[OUT_MS  + i * B_N + b] = M;
        out[OUT_EVS + i * B_N + b] = Ev;
        out[OUT_IVS + i * B_N + b] = Iv;
        out[OUT_MVS + i * B_N + b] = Mv;
        ring[i * RW + (7 - b)] = eif;        // new col 0 slot
        ring[i * RW + (8 - b)] = eif;        // old live slot's final value
        fing[b * N_ + i] = eif;
        BARRIER();                           // fin_l visible for next batch's correction
    }

    out[i * 6 + 0] = M;  out[i * 6 + 1] = E;  out[i * 6 + 2] = I;
    out[i * 6 + 3] = Mv; out[i * 6 + 4] = Ev; out[i * 6 + 5] = Iv;
}

// k_post: blocks 0..511 copy final hE; blocks 512..573 compute eeg rows.
__global__ void k_post(const float* __restrict__ ring, const float* __restrict__ fing,
                       const float* __restrict__ lm, float* __restrict__ out) {
    int bi = blockIdx.x;
    int lane = threadIdx.x;        // 64 threads
    if (bi < N_) {
#pragma unroll
        for (int q = 0; q < 6; q++) {
            int k = lane + 64 * q;
            if (k < D_) out[OUT_HE + bi * D_ + k] = ring[bi * RW + k];
        }
    } else {
        int o = bi - N_;
        float lv[8];
#pragma unroll
        for (int q = 0; q < 8; q++) lv[q] = lm[o * N_ + 64 * q + lane];
        for (int b = 0; b < B_N; b++) {
            float p = 0.f;
#pragma unroll
            for (int q = 0; q < 8; q++) p = fmaf(lv[q], fing[b * N_ + 64 * q + lane], p);
#pragma unroll
            for (int off = 32; off > 0; off >>= 1) p += __shfl_down(p, off, 64);
            if (lane == 0) out[OUT_EEG + o * B_N + b] = 0.0005f * p;
        }
    }
}

extern "C" void kernel_launch(void* const* d_in, const int* in_sizes, int n_in,
                              void* d_out, int out_size, void* d_ws, size_t ws_size,
                              hipStream_t stream) {
    const float* input    = (const float*)d_in[0];
    const float* noise_in = (const float*)d_in[1];
    // d_in[2] = noise_out: unused by the reference
    const float* hx       = (const float*)d_in[3];
    const float* hE       = (const float*)d_in[4];
    const float* wbb      = (const float*)d_in[5];
    const float* sc       = (const float*)d_in[6];
    const float* lm       = (const float*)d_in[7];
    const int*   delays   = (const int*)d_in[8];
    float* out = (float*)d_out;

    // workspace carve-up (floats)
    float* F    = (float*)d_ws;
    float* drv  = F;                       // 321*512 = 164352 (row 320 = prefetch pad)
    float* wsm  = drv + 164352;            // 262144
    float* ring = wsm + 262144;            // 200704 (512 x 392)
    float* bp8  = ring + 200704;           // 32768  (8b x 8jb x 512)
    float* rsw  = bp8 + 32768;             // 512
    float* ssq  = rsw + 512;               // 512
    float* s0w  = ssq + 512;               // 13*512
    int*   s0j  = (int*)(s0w + N_ * SMAX); // 13*512
    int*   s0c  = s0j + N_ * SMAX;         // 512
    float* s1w  = (float*)(s0c + N_);      // 28*512
    int*   s1p  = (int*)(s1w + N_ * CMAX); // 28*512
    float* fing = (float*)(s1p + N_ * CMAX); // 8*512

    k_prep<<<N_, 256, 0, stream>>>(input, noise_in, drv, wbb, sc, hE, delays,
                                   wsm, ring, rsw, ssq, s0w, s0j, s0c, s1w, s1p);
    k_hist<<<512, 512, 0, stream>>>(wsm, delays, ring, bp8);
    k_hidden<<<1, N_, 0, stream>>>(drv, hE, hx, bp8, ssq, rsw,
                                   s0w, s0j, s0c, s1w, s1p, ring, fing, out);
    k_post<<<N_ + O_, 64, 0, stream>>>(ring, fing, lm, out);
}